// Round 10
// baseline (85.187 us; speedup 1.0000x reference)
//
#include <hip/hip_runtime.h>
#include <hip/hip_bf16.h>
#include <stdint.h>

#define DEV static __device__ __forceinline__

typedef __attribute__((ext_vector_type(8)))  short    s16x8;
typedef __attribute__((ext_vector_type(4)))  short    s16x4;
typedef __attribute__((ext_vector_type(8)))  __bf16   bf16x8;
typedef __attribute__((ext_vector_type(4)))  float    f32x4;
typedef __attribute__((ext_vector_type(16))) float    f32x16;
typedef __attribute__((ext_vector_type(2)))  unsigned u32x2;
typedef __attribute__((ext_vector_type(4)))  unsigned u32x4;

DEV short f2b(float f){           // round-to-nearest-even f32 -> bf16
  union{float f; uint32_t i;} x; x.f = f;
  uint32_t r = x.i + 0x7FFFu + ((x.i >> 16) & 1u);
  return (short)(r >> 16);
}
DEV bf16x8 as_bf(s16x8 v){ return __builtin_bit_cast(bf16x8, v); }
DEV float fexp2(float x){ return __builtin_amdgcn_exp2f(x); }   // v_exp_f32: 2^x
DEV f32x4 mf(s16x8 a, s16x8 b, f32x4 c){
  return __builtin_amdgcn_mfma_f32_16x16x32_bf16(as_bf(a), as_bf(b), c, 0, 0, 0);
}
DEV f32x16 mf32(s16x8 a, s16x8 b, f32x16 c){
  return __builtin_amdgcn_mfma_f32_32x32x16_bf16(as_bf(a), as_bf(b), c, 0, 0, 0);
}

DEV void gload_lds16(const void* g, void* l){
  __builtin_amdgcn_global_load_lds((const __attribute__((address_space(1))) void*)g,
                                   (__attribute__((address_space(3))) void*)l, 16, 0, 0);
}

#if __has_builtin(__builtin_amdgcn_permlane32_swap)
DEV void pswap2(unsigned a, unsigned b, unsigned& x, unsigned& y){
  u32x2 rr = __builtin_amdgcn_permlane32_swap(a, b, false, false);
  x = rr[0]; y = rr[1];
}
DEV float partner32(float v, int hi){
  unsigned u = __builtin_bit_cast(unsigned, v);
  u32x2 rr = __builtin_amdgcn_permlane32_swap(u, u, false, false);
  return __builtin_bit_cast(float, hi ? rr[0] : rr[1]);
}
#else
DEV void pswap2(unsigned a, unsigned b, unsigned& x, unsigned& y){
  unsigned pa_ = (unsigned)__shfl_xor((int)a, 32, 64);
  unsigned pb_ = (unsigned)__shfl_xor((int)b, 32, 64);
  int lo = ((threadIdx.x & 63) < 32);
  x = lo ? a   : pb_;
  y = lo ? pa_ : b;
}
DEV float partner32(float v, int hi){ (void)hi; return __shfl_xor(v, 32, 64); }
#endif

// ---------------- fused convert f32 -> bf16 for query/key_in/value (HBM-roofline stream) ----------------
__global__ __launch_bounds__(256) void k_conv3(const float* __restrict__ q,
                                               const float* __restrict__ k,
                                               const float* __restrict__ v,
                                               short* __restrict__ out){
  int z = blockIdx.z;
  const float* in = (z == 0) ? q : (z == 1) ? k : v;
  int i = (blockIdx.x * 256 + threadIdx.x) * 4;
  float4 val = *(const float4*)(in + i);
  short o[4] = { f2b(val.x), f2b(val.y), f2b(val.z), f2b(val.w) };
  *(uint2*)(out + (size_t)z * 4194304 + i) = *(uint2*)o;
}

// ------------- fused weight transpose+convert: 4x w[512][512] f32 -> wt[n][k] bf16 -------------
__global__ __launch_bounds__(256) void k_wt4(const float* __restrict__ w0,
                                             const float* __restrict__ w1,
                                             const float* __restrict__ w2,
                                             const float* __restrict__ w3,
                                             short* __restrict__ wt){
  __shared__ float tile[32][33];
  int z = blockIdx.z;
  const float* w = (z == 0) ? w0 : (z == 1) ? w1 : (z == 2) ? w2 : w3;
  short* o = wt + (size_t)z * 262144;
  int bx = blockIdx.x * 32, by = blockIdx.y * 32;   // bx: n-block, by: k-block
  int tx = threadIdx.x, ty = threadIdx.y;           // (32, 8)
  for (int j = 0; j < 32; j += 8)
    tile[ty + j][tx] = w[(size_t)(by + ty + j) * 512 + bx + tx];
  __syncthreads();
  for (int j = 0; j < 32; j += 8)
    o[(size_t)(bx + ty + j) * 512 + by + tx] = f2b(tile[tx][ty + j]);
}

// ---------------- RoPE cos/sin table: tab[s][j][{cos,sin}], s<1024, j<32 ----------------
__global__ __launch_bounds__(256) void k_table(float* __restrict__ tab){
  int idx = blockIdx.x * 256 + threadIdx.x;   // 32768
  int s = idx >> 5, j = idx & 31;
  float inv = __expf(-(float)j * (1.0f / 32.0f) * logf(10000.0f));
  float ang = (float)s * inv;
  tab[idx * 2 + 0] = cosf(ang);
  tab[idx * 2 + 1] = sinf(ang);
}

// ---------------- QKV GEMM (bf16 in) + RoPE/layout epilogues ----------------
// 128x128 tile, BK=32, 2-phase double-buffer (stage(next) -> compute(cur) -> barrier),
// both slabs via global_load_lds with 4-slot XOR swizzle (slot ^ row&3) -> ~2-way reads.
__global__ __launch_bounds__(256) void k_qkv(const short* __restrict__ Xb,
                                             const short* __restrict__ Wcat,
                                             const float* __restrict__ tab,
                                             short* __restrict__ Qa,
                                             short* __restrict__ Ka,
                                             short* __restrict__ Vt){
  __shared__ __align__(16) short Al[2][4096];    // [128 rows][32 k] swizzled
  __shared__ __align__(16) short Bl[2][4096];
  const int t = threadIdx.x, w = t >> 6, lane = t & 63, fr = lane & 15, fg = lane >> 4;
  const int sel = blockIdx.y >> 2;
  const short* X = Xb + (size_t)sel * 4194304;
  const int bm = blockIdx.x * 128, bn = blockIdx.y * 128;
  const int wm = (w >> 1) * 64, wn = (w & 1) * 64;

  auto stage = [&](int buf, int k0){
#pragma unroll
    for (int q = 0; q < 2; q++){
      int lin = q * 256 + t;
      int row = lin >> 2, sl = lin & 3;
      int gs = (sl ^ (row & 3)) * 8;             // pre-swizzled global source (rule #21)
      gload_lds16(X    + (size_t)(bm + row) * 512 + k0 + gs, &Al[buf][(q * 256 + w * 64) * 8]);
      gload_lds16(Wcat + (size_t)(bn + row) * 512 + k0 + gs, &Bl[buf][(q * 256 + w * 64) * 8]);
    }
  };

  f32x4 acc[4][4] = {};
  stage(0, 0);
  __syncthreads();
  int cur = 0;
  for (int t16 = 0; t16 < 16; ++t16){
    if (t16 < 15) stage(cur ^ 1, (t16 + 1) * 32);
    s16x8 af[4], bv[4];
#pragma unroll
    for (int f = 0; f < 4; f++){
      int ra = wm + f * 16 + fr;
      af[f] = *(const s16x8*)(&Al[cur][ra * 32 + ((fg ^ (ra & 3)) * 8)]);
      int rb = wn + f * 16 + fr;
      bv[f] = *(const s16x8*)(&Bl[cur][rb * 32 + ((fg ^ (rb & 3)) * 8)]);
    }
#pragma unroll
    for (int i = 0; i < 4; i++)
#pragma unroll
      for (int jj = 0; jj < 4; jj++)
        acc[i][jj] = mf(af[i], bv[jj], acc[i][jj]);
    __syncthreads();
    cur ^= 1;
  }

  const int row0 = bm + wm + fg * 4;         // + i*16 + r
  const int b = row0 >> 10;
  const int s_base = row0 & 1023;
  const int hh = (((blockIdx.y & 3) * 128) + wn) >> 6;   // head 0..7
  if (sel < 2){
    const float scale = (sel == 0) ? 0.125f * 1.44269504f : 1.0f;
    short* out = (sel == 0) ? Qa : Ka;
#pragma unroll
    for (int i = 0; i < 4; i++)
#pragma unroll
      for (int jj = 0; jj < 2; jj++){
        int d = jj * 16 + fr;                // 0..31
#pragma unroll
        for (int r = 0; r < 4; r++){
          int s = s_base + i * 16 + r;
          float2 cs = *(const float2*)(tab + (size_t)(s * 32 + d) * 2);
          float x1 = acc[i][jj][r], x2 = acc[i][jj + 2][r];
          size_t ob = ((size_t)((b * 8 + hh) * 1024 + s)) * 64 + d;
          out[ob]      = f2b((x1 * cs.x - x2 * cs.y) * scale);
          out[ob + 32] = f2b((x2 * cs.x + x1 * cs.y) * scale);
        }
      }
  } else {
#pragma unroll
    for (int i = 0; i < 4; i++)
#pragma unroll
      for (int jj = 0; jj < 4; jj++){
        int d = jj * 16 + fr;
        s16x4 pk;
#pragma unroll
        for (int r = 0; r < 4; r++) pk[r] = f2b(acc[i][jj][r]);
        size_t ob = ((size_t)((b * 8 + hh) * 64 + d)) * 1024 + s_base + i * 16;
        *(s16x4*)(Vt + ob) = pk;
      }
  }
}

// ---------------- causal flash attention: 32x32 MFMA, in-register softmax ----------------
__global__ __launch_bounds__(128) void k_attn(const short* __restrict__ Qb,
                                              const short* __restrict__ Kb,
                                              const short* __restrict__ Vt,
                                              short* __restrict__ O){
  __shared__ __align__(16) short KL[2][4096];
  __shared__ __align__(16) short VL[2][4096];
  const int bid = blockIdx.x;
  const int podr[16] = {15,14,13,12, 0,1,2,3, 11,10,9,8, 4,5,6,7};
  const int Bi = podr[bid >> 6];
  const int bh = bid & 63;                   // bid%8 == bh%8 -> bh pinned to one XCD
  const int B0 = Bi * 64;
  const int t = threadIdx.x, w = t >> 6, lane = t & 63;
  const int col = lane & 31, hi = lane >> 5;
  const short* Qp = Qb + (size_t)bh * 65536;
  const short* Kp = Kb + (size_t)bh * 65536;
  const short* Vp = Vt + (size_t)bh * 65536;  // V^T: [64 d][1024 kv]
  const int qrow = B0 + 2 * col + w;          // this lane's q row (softmax axis)

  s16x8 qb[4];
#pragma unroll
  for (int ks = 0; ks < 4; ks++)
    qb[ks] = *(const s16x8*)(Qp + (size_t)qrow * 64 + ks * 16 + hi * 8);

  int crow[16];
#pragma unroll
  for (int r = 0; r < 16; r++) crow[r] = (r & 3) + 8 * (r >> 2) + 4 * hi;

  f32x16 oacc[2] = {};                       // O[q(crow)][d = df*32 + col]
  float m = -1e30f, l = 0.f;

  auto stage = [&](int buf, int kv0){
#pragma unroll
    for (int R = 0; R < 4; R++){
      int lin = R * 128 + w * 64 + lane;     // 0..511 : row = lin/8, 16B-slot = lin%8
      int row = lin >> 3, slot = lin & 7;
      int gs = ((slot ^ (row & 7)) * 8);     // inverse-swizzled global source (rule #21)
      gload_lds16(Kp + (size_t)(kv0 + row) * 64 + gs, &KL[buf][(R * 128 + w * 64) * 8]);
      gload_lds16(Vp + (size_t)row * 1024 + kv0 + gs, &VL[buf][(R * 128 + w * 64) * 8]);
    }
  };

  stage(0, 0);
  __syncthreads();

  int cur = 0;
  for (int kv0 = 0; kv0 <= B0; kv0 += 64){
    if (kv0 < B0) stage(cur ^ 1, kv0 + 64);  // issue next-chunk loads before compute
    f32x16 sc[2];
#pragma unroll
    for (int f = 0; f < 2; f++){
      f32x16 s = {};
      int row = f * 32 + col, rx = row & 7;
#pragma unroll
      for (int ks = 0; ks < 4; ks++){
        s16x8 ka = *(const s16x8*)(&KL[cur][row * 64 + ((ks * 2 + hi) ^ rx) * 8]);
        s = mf32(ka, qb[ks], s);
      }
      sc[f] = s;
    }
    if (kv0 == B0){
#pragma unroll
      for (int f = 0; f < 2; f++)
#pragma unroll
        for (int r = 0; r < 16; r++){
          int kv = kv0 + f * 32 + crow[r];
          if (kv > qrow) sc[f][r] = -1e30f;
        }
    }
    float tm = -1e30f;
#pragma unroll
    for (int f = 0; f < 2; f++)
#pragma unroll
      for (int r = 0; r < 16; r++) tm = fmaxf(tm, sc[f][r]);
    tm = fmaxf(tm, partner32(tm, hi));
    if (!__all(tm <= m + 8.f)){
      float mn = fmaxf(m, tm);
      float corr = fexp2(m - mn);
      m = mn;
      l *= corr;
      float cpv[16];
#pragma unroll
      for (int r = 0; r < 16; r++) cpv[r] = __shfl(corr, crow[r], 64);
#pragma unroll
      for (int r = 0; r < 16; r++){ oacc[0][r] *= cpv[r]; oacc[1][r] *= cpv[r]; }
    }
    float rs = 0.f;
    unsigned wq[2][8];
#pragma unroll
    for (int f = 0; f < 2; f++)
#pragma unroll
      for (int i = 0; i < 8; i++){
        float p0 = fexp2(sc[f][2 * i]     - m);
        float p1 = fexp2(sc[f][2 * i + 1] - m);
        rs += p0 + p1;
        wq[f][i] = (unsigned)(uint16_t)f2b(p0) | ((unsigned)(uint16_t)f2b(p1) << 16);
      }
    rs += partner32(rs, hi);
    l += rs;
    s16x8 pa[4];
#pragma unroll
    for (int f = 0; f < 2; f++)
#pragma unroll
      for (int half = 0; half < 2; half++){
        unsigned w0, w1, w2, w3;
        pswap2(wq[f][half * 4 + 0], wq[f][half * 4 + 2], w0, w2);
        pswap2(wq[f][half * 4 + 1], wq[f][half * 4 + 3], w1, w3);
        u32x4 uv = { w0, w1, w2, w3 };
        pa[f * 2 + half] = __builtin_bit_cast(s16x8, uv);
      }
#pragma unroll
    for (int ks = 0; ks < 4; ks++)
#pragma unroll
      for (int df = 0; df < 2; df++){
        int row = df * 32 + col;
        s16x8 vb = *(const s16x8*)(&VL[cur][row * 64 + ((ks * 2 + hi) ^ (row & 7)) * 8]);
        oacc[df] = mf32(pa[ks], vb, oacc[df]);
      }
    if (kv0 < B0) __syncthreads();           // drains stage loads (vmcnt) + protects buffers
    cur ^= 1;
  }

  const int b = bh >> 3, h = bh & 7;
  float lf[16];
#pragma unroll
  for (int r = 0; r < 16; r++) lf[r] = __shfl(l, crow[r], 64);
#pragma unroll
  for (int r = 0; r < 16; r++){
    int qq = B0 + 2 * crow[r] + w;
    float inv = 1.0f / lf[r];
    O[(size_t)(b * 1024 + qq) * 512 + h * 64 + col]      = f2b(oacc[0][r] * inv);
    O[(size_t)(b * 1024 + qq) * 512 + h * 64 + 32 + col] = f2b(oacc[1][r] * inv);
  }
}

// ---------------- final GEMM: BK=64 dbuf, swizzled 128B rows, f32 out ----------------
__global__ __launch_bounds__(256, 2) void k_gemm_out(const short* __restrict__ X,
                                                     const short* __restrict__ Wt,
                                                     float* __restrict__ C){
  __shared__ __align__(16) short Al[2][8192];   // [128 rows][64 k] swizzled 16KB each
  __shared__ __align__(16) short Bl[2][8192];
  const int t = threadIdx.x;
  const int w = t >> 6, lane = t & 63, fr = lane & 15, fg = lane >> 4;
  const int bm = blockIdx.x * 128, bn = blockIdx.y * 128;
  const int wm = (w >> 1) * 64, wn = (w & 1) * 64;

  auto stage = [&](int buf, int k0){
#pragma unroll
    for (int q = 0; q < 4; q++){
      int lin = q * 256 + t;
      int row = lin >> 3, sl = lin & 7;
      int gs = (sl ^ (row & 7)) * 8;
      gload_lds16(X  + (size_t)(bm + row) * 512 + k0 + gs, &Al[buf][(q * 256 + w * 64) * 8]);
      gload_lds16(Wt + (size_t)(bn + row) * 512 + k0 + gs, &Bl[buf][(q * 256 + w * 64) * 8]);
    }
  };

  f32x4 acc[4][4] = {};
  stage(0, 0);
  __syncthreads();
  int cur = 0;
  for (int t8 = 0; t8 < 8; ++t8){
    if (t8 < 7) stage(cur ^ 1, (t8 + 1) * 64);
#pragma unroll
    for (int kk = 0; kk < 2; kk++){
      s16x8 af[4], bv[4];
#pragma unroll
      for (int f = 0; f < 4; f++){
        int rowa = wm + f * 16 + fr;
        af[f] = *(const s16x8*)(&Al[cur][rowa * 64 + ((kk * 4 + fg) ^ (rowa & 7)) * 8]);
        int rowb = wn + f * 16 + fr;
        bv[f] = *(const s16x8*)(&Bl[cur][rowb * 64 + ((kk * 4 + fg) ^ (rowb & 7)) * 8]);
      }
#pragma unroll
      for (int i = 0; i < 4; i++)
#pragma unroll
        for (int jj = 0; jj < 4; jj++)
          acc[i][jj] = mf(af[i], bv[jj], acc[i][jj]);
    }
    __syncthreads();
    cur ^= 1;
  }
  const int row0 = bm + wm + fg * 4;
  const int col0 = bn + wn + fr;
#pragma unroll
  for (int i = 0; i < 4; i++)
#pragma unroll
    for (int jj = 0; jj < 4; jj++)
#pragma unroll
      for (int r = 0; r < 4; r++)
        C[(size_t)(row0 + i * 16 + r) * 512 + col0 + jj * 16] = acc[i][jj][r];
}

extern "C" void kernel_launch(void* const* d_in, const int* in_sizes, int n_in,
                              void* d_out, int out_size, void* d_ws, size_t ws_size,
                              hipStream_t stream){
  const float* query  = (const float*)d_in[0];
  const float* value  = (const float*)d_in[1];
  const float* key_in = (const float*)d_in[2];
  const float* Wq     = (const float*)d_in[3];
  const float* Wk     = (const float*)d_in[4];
  const float* Wv     = (const float*)d_in[5];
  const float* Wo     = (const float*)d_in[6];

  char* ws = (char*)d_ws;
  const size_t MB = 1ull << 20;
  short* Xb   = (short*)(ws);                    // 24 MB: Xq,Xk,Xv bf16 (Xq reused as Oa)
  short* Wcat = (short*)(ws + 24 * MB);          // 2 MB: Wq,Wk,Wv,Wo transposed
  float* tab  = (float*)(ws + 26 * MB);          // 256 KB
  short* Qa   = (short*)(ws + 26 * MB + 256 * 1024);   // 8 MB
  short* Ka   = (short*)((char*)Qa + 8 * MB);          // 8 MB
  short* Va   = (short*)((char*)Ka + 8 * MB);          // 8 MB  (ends at 50.25 MB)
  short* Oa   = Xb;                              // reuse Xq region after k_qkv
  short* Wot  = Wcat + 786432;                   // Wo^T block

  k_conv3<<<dim3(4096, 1, 3), 256, 0, stream>>>(query, key_in, value, Xb);
  k_wt4<<<dim3(16, 16, 4), dim3(32, 8), 0, stream>>>(Wq, Wk, Wv, Wo, Wcat);
  k_table<<<128, 256, 0, stream>>>(tab);

  k_qkv<<<dim3(64, 12), 256, 0, stream>>>(Xb, Wcat, tab, Qa, Ka, Va);

  k_attn<<<1024, 128, 0, stream>>>(Qa, Ka, Va, Oa);

  k_gemm_out<<<dim3(64, 4), 256, 0, stream>>>(Oa, Wot, (float*)d_out);
}

// Round 11
// 83.971 us; speedup vs baseline: 1.0145x; 1.0145x over previous
//
#include <hip/hip_runtime.h>
#include <hip/hip_bf16.h>
#include <stdint.h>

#define DEV static __device__ __forceinline__

typedef __attribute__((ext_vector_type(8)))  short    s16x8;
typedef __attribute__((ext_vector_type(4)))  short    s16x4;
typedef __attribute__((ext_vector_type(8)))  __bf16   bf16x8;
typedef __attribute__((ext_vector_type(2)))  __bf16   bf16x2;
typedef __attribute__((ext_vector_type(4)))  float    f32x4;
typedef __attribute__((ext_vector_type(16))) float    f32x16;
typedef __attribute__((ext_vector_type(2)))  unsigned u32x2;
typedef __attribute__((ext_vector_type(4)))  unsigned u32x4;

DEV short f2b(float f){           // round-to-nearest-even f32 -> bf16
  union{float f; uint32_t i;} x; x.f = f;
  uint32_t r = x.i + 0x7FFFu + ((x.i >> 16) & 1u);
  return (short)(r >> 16);
}
DEV unsigned packbf(float a, float b){   // v_cvt_pk_bf16_f32 path (RTNE)
  bf16x2 v = { (__bf16)a, (__bf16)b };
  return __builtin_bit_cast(unsigned, v);
}
DEV bf16x8 as_bf(s16x8 v){ return __builtin_bit_cast(bf16x8, v); }
DEV float fexp2(float x){ return __builtin_amdgcn_exp2f(x); }   // v_exp_f32: 2^x
DEV f32x4 mf(s16x8 a, s16x8 b, f32x4 c){
  return __builtin_amdgcn_mfma_f32_16x16x32_bf16(as_bf(a), as_bf(b), c, 0, 0, 0);
}
DEV f32x16 mf32(s16x8 a, s16x8 b, f32x16 c){
  return __builtin_amdgcn_mfma_f32_32x32x16_bf16(as_bf(a), as_bf(b), c, 0, 0, 0);
}

DEV void gload_lds16(const void* g, void* l){
  __builtin_amdgcn_global_load_lds((const __attribute__((address_space(1))) void*)g,
                                   (__attribute__((address_space(3))) void*)l, 16, 0, 0);
}

#if __has_builtin(__builtin_amdgcn_permlane32_swap)
DEV void pswap2(unsigned a, unsigned b, unsigned& x, unsigned& y){
  u32x2 rr = __builtin_amdgcn_permlane32_swap(a, b, false, false);
  x = rr[0]; y = rr[1];
}
DEV float partner32(float v, int hi){
  unsigned u = __builtin_bit_cast(unsigned, v);
  u32x2 rr = __builtin_amdgcn_permlane32_swap(u, u, false, false);
  return __builtin_bit_cast(float, hi ? rr[0] : rr[1]);
}
#else
DEV void pswap2(unsigned a, unsigned b, unsigned& x, unsigned& y){
  unsigned pa_ = (unsigned)__shfl_xor((int)a, 32, 64);
  unsigned pb_ = (unsigned)__shfl_xor((int)b, 32, 64);
  int lo = ((threadIdx.x & 63) < 32);
  x = lo ? a   : pb_;
  y = lo ? pa_ : b;
}
DEV float partner32(float v, int hi){ (void)hi; return __shfl_xor(v, 32, 64); }
#endif

// ---------------- fused convert f32 -> bf16 for query/key_in/value (HBM-roofline stream) ----------------
__global__ __launch_bounds__(256) void k_conv3(const float* __restrict__ q,
                                               const float* __restrict__ k,
                                               const float* __restrict__ v,
                                               short* __restrict__ out){
  int z = blockIdx.z;
  const float* in = (z == 0) ? q : (z == 1) ? k : v;
  int i = (blockIdx.x * 256 + threadIdx.x) * 4;
  float4 val = *(const float4*)(in + i);
  short o[4] = { f2b(val.x), f2b(val.y), f2b(val.z), f2b(val.w) };
  *(uint2*)(out + (size_t)z * 4194304 + i) = *(uint2*)o;
}

// ------------- fused weight transpose+convert: 4x w[512][512] f32 -> wt[n][k] bf16 -------------
__global__ __launch_bounds__(256) void k_wt4(const float* __restrict__ w0,
                                             const float* __restrict__ w1,
                                             const float* __restrict__ w2,
                                             const float* __restrict__ w3,
                                             short* __restrict__ wt){
  __shared__ float tile[32][33];
  int z = blockIdx.z;
  const float* w = (z == 0) ? w0 : (z == 1) ? w1 : (z == 2) ? w2 : w3;
  short* o = wt + (size_t)z * 262144;
  int bx = blockIdx.x * 32, by = blockIdx.y * 32;   // bx: n-block, by: k-block
  int tx = threadIdx.x, ty = threadIdx.y;           // (32, 8)
  for (int j = 0; j < 32; j += 8)
    tile[ty + j][tx] = w[(size_t)(by + ty + j) * 512 + bx + tx];
  __syncthreads();
  for (int j = 0; j < 32; j += 8)
    o[(size_t)(bx + ty + j) * 512 + by + tx] = f2b(tile[tx][ty + j]);
}

// ---------------- RoPE cos/sin table: tab[s][j][{cos,sin}], s<1024, j<32 ----------------
__global__ __launch_bounds__(256) void k_table(float* __restrict__ tab){
  int idx = blockIdx.x * 256 + threadIdx.x;   // 32768
  int s = idx >> 5, j = idx & 31;
  float inv = __expf(-(float)j * (1.0f / 32.0f) * logf(10000.0f));
  float ang = (float)s * inv;
  tab[idx * 2 + 0] = cosf(ang);
  tab[idx * 2 + 1] = sinf(ang);
}

// ---------------- QKV GEMM (bf16 in) + RoPE/layout epilogues ----------------
// 128x128 tile, BK=32, 2-phase double-buffer, swizzled global_load_lds slabs.
__global__ __launch_bounds__(256) void k_qkv(const short* __restrict__ Xb,
                                             const short* __restrict__ Wcat,
                                             const float* __restrict__ tab,
                                             short* __restrict__ Qa,
                                             short* __restrict__ Ka,
                                             short* __restrict__ Vt){
  __shared__ __align__(16) short Al[2][4096];    // [128 rows][32 k] swizzled
  __shared__ __align__(16) short Bl[2][4096];
  const int t = threadIdx.x, w = t >> 6, lane = t & 63, fr = lane & 15, fg = lane >> 4;
  const int sel = blockIdx.y >> 2;
  const short* X = Xb + (size_t)sel * 4194304;
  const int bm = blockIdx.x * 128, bn = blockIdx.y * 128;
  const int wm = (w >> 1) * 64, wn = (w & 1) * 64;

  auto stage = [&](int buf, int k0){
#pragma unroll
    for (int q = 0; q < 2; q++){
      int lin = q * 256 + t;
      int row = lin >> 2, sl = lin & 3;
      int gs = (sl ^ (row & 3)) * 8;             // pre-swizzled global source (rule #21)
      gload_lds16(X    + (size_t)(bm + row) * 512 + k0 + gs, &Al[buf][(q * 256 + w * 64) * 8]);
      gload_lds16(Wcat + (size_t)(bn + row) * 512 + k0 + gs, &Bl[buf][(q * 256 + w * 64) * 8]);
    }
  };

  f32x4 acc[4][4] = {};
  stage(0, 0);
  __syncthreads();
  int cur = 0;
  for (int t16 = 0; t16 < 16; ++t16){
    if (t16 < 15) stage(cur ^ 1, (t16 + 1) * 32);
    s16x8 af[4], bv[4];
#pragma unroll
    for (int f = 0; f < 4; f++){
      int ra = wm + f * 16 + fr;
      af[f] = *(const s16x8*)(&Al[cur][ra * 32 + ((fg ^ (ra & 3)) * 8)]);
      int rb = wn + f * 16 + fr;
      bv[f] = *(const s16x8*)(&Bl[cur][rb * 32 + ((fg ^ (rb & 3)) * 8)]);
    }
#pragma unroll
    for (int i = 0; i < 4; i++)
#pragma unroll
      for (int jj = 0; jj < 4; jj++)
        acc[i][jj] = mf(af[i], bv[jj], acc[i][jj]);
    __syncthreads();
    cur ^= 1;
  }

  const int row0 = bm + wm + fg * 4;         // + i*16 + r
  const int b = row0 >> 10;
  const int s_base = row0 & 1023;
  const int hh = (((blockIdx.y & 3) * 128) + wn) >> 6;   // head 0..7
  if (sel < 2){
    const float scale = (sel == 0) ? 0.125f * 1.44269504f : 1.0f;
    short* out = (sel == 0) ? Qa : Ka;
#pragma unroll
    for (int i = 0; i < 4; i++)
#pragma unroll
      for (int jj = 0; jj < 2; jj++){
        int d = jj * 16 + fr;                // 0..31
#pragma unroll
        for (int r = 0; r < 4; r++){
          int s = s_base + i * 16 + r;
          float2 cs = *(const float2*)(tab + (size_t)(s * 32 + d) * 2);
          float x1 = acc[i][jj][r], x2 = acc[i][jj + 2][r];
          size_t ob = ((size_t)((b * 8 + hh) * 1024 + s)) * 64 + d;
          out[ob]      = f2b((x1 * cs.x - x2 * cs.y) * scale);
          out[ob + 32] = f2b((x2 * cs.x + x1 * cs.y) * scale);
        }
      }
  } else {
#pragma unroll
    for (int i = 0; i < 4; i++)
#pragma unroll
      for (int jj = 0; jj < 4; jj++){
        int d = jj * 16 + fr;
        s16x4 pk;
#pragma unroll
        for (int r = 0; r < 4; r++) pk[r] = f2b(acc[i][jj][r]);
        size_t ob = ((size_t)((b * 8 + hh) * 64 + d)) * 1024 + s_base + i * 16;
        *(s16x4*)(Vt + ob) = pk;
      }
  }
}

// ---------------- causal flash attention: 4-wave blocks, 128 interleaved q-rows ----------------
// Block = 256 thr (4 waves) on q rows [B0, B0+128), wave w owns rows B0 + 4c + w so all
// waves share the causal kv range [0, B0+128). One 16KB K/V stage feeds 4 waves.
// Swapped QK^T, in-register softmax (tree reductions), cvt_pk pack + permlane32 transpose.
__global__ __launch_bounds__(256) void k_attn(const short* __restrict__ Qb,
                                              const short* __restrict__ Kb,
                                              const short* __restrict__ Vt,
                                              short* __restrict__ O){
  __shared__ __align__(16) short KL[2][4096];
  __shared__ __align__(16) short VL[2][4096];
  const int bid = blockIdx.x;
  // co-CU pairing (g, g+4): Bi sums to 7 -> 18 bodies per CU, heavy groups first
  const int BiMap[8] = {7,6,5,4, 0,1,2,3};
  const int Bi = BiMap[bid >> 6];
  const int bh = bid & 63;                   // bid%8 == bh%8 -> bh pinned to one XCD
  const int B0 = Bi * 128;
  const int KVEND = B0 + 128;
  const int t = threadIdx.x, w = t >> 6, lane = t & 63;
  const int col = lane & 31, hi = lane >> 5;
  const short* Qp = Qb + (size_t)bh * 65536;
  const short* Kp = Kb + (size_t)bh * 65536;
  const short* Vp = Vt + (size_t)bh * 65536;  // V^T: [64 d][1024 kv]
  const int qrow = B0 + 4 * col + w;          // this lane's q row (softmax axis)

  s16x8 qb[4];
#pragma unroll
  for (int ks = 0; ks < 4; ks++)
    qb[ks] = *(const s16x8*)(Qp + (size_t)qrow * 64 + ks * 16 + hi * 8);

  int crow[16];
#pragma unroll
  for (int r = 0; r < 16; r++) crow[r] = (r & 3) + 8 * (r >> 2) + 4 * hi;

  f32x16 oacc[2] = {};                       // O[q(crow)][d = df*32 + col]
  float m = -1e30f, l = 0.f;

  auto stage = [&](int buf, int kv0){
#pragma unroll
    for (int R = 0; R < 2; R++){
      int lin = R * 256 + w * 64 + lane;     // 0..511 : row = lin/8, 16B-slot = lin%8
      int row = lin >> 3, slot = lin & 7;
      int gs = ((slot ^ (row & 7)) * 8);     // inverse-swizzled global source (rule #21)
      gload_lds16(Kp + (size_t)(kv0 + row) * 64 + gs, &KL[buf][(R * 256 + w * 64) * 8]);
      gload_lds16(Vp + (size_t)row * 1024 + kv0 + gs, &VL[buf][(R * 256 + w * 64) * 8]);
    }
  };

  stage(0, 0);
  __syncthreads();

  int cur = 0;
  for (int kv0 = 0; kv0 < KVEND; kv0 += 64){
    const bool hasNext = (kv0 + 64 < KVEND);
    if (hasNext) stage(cur ^ 1, kv0 + 64);   // issue next-chunk loads before compute
    // ---- QK^T (swapped): D[kv][q], A = K chunk, B = Q ----
    __builtin_amdgcn_s_setprio(1);
    f32x16 sc[2];
#pragma unroll
    for (int f = 0; f < 2; f++){
      f32x16 s = {};
      int row = f * 32 + col, rx = row & 7;
#pragma unroll
      for (int ks = 0; ks < 4; ks++){
        s16x8 ka = *(const s16x8*)(&KL[cur][row * 64 + ((ks * 2 + hi) ^ rx) * 8]);
        s = mf32(ka, qb[ks], s);
      }
      sc[f] = s;
    }
    __builtin_amdgcn_s_setprio(0);
    // ---- causal mask (bodies overlapping the q range) ----
    if (kv0 >= B0){
#pragma unroll
      for (int f = 0; f < 2; f++)
#pragma unroll
        for (int r = 0; r < 16; r++){
          int kv = kv0 + f * 32 + crow[r];
          if (kv > qrow) sc[f][r] = -1e30f;
        }
    }
    // ---- softmax: tree max, defer-max rescale ----
    float mx[16];
#pragma unroll
    for (int r = 0; r < 16; r++) mx[r] = fmaxf(sc[0][r], sc[1][r]);
#pragma unroll
    for (int off = 8; off >= 1; off >>= 1)
#pragma unroll
      for (int r = 0; r < off; r++) mx[r] = fmaxf(mx[r], mx[r + off]);
    float tm = fmaxf(mx[0], partner32(mx[0], hi));
    if (!__all(tm <= m + 8.f)){
      float mn = fmaxf(m, tm);
      float corr = fexp2(m - mn);
      m = mn;
      l *= corr;
      float cpv[16];
#pragma unroll
      for (int r = 0; r < 16; r++) cpv[r] = __shfl(corr, crow[r], 64);
#pragma unroll
      for (int r = 0; r < 16; r++){ oacc[0][r] *= cpv[r]; oacc[1][r] *= cpv[r]; }
    }
    // ---- P = exp2(sc - m): cvt_pk pack + tree sum ----
    float p[32];
#pragma unroll
    for (int f = 0; f < 2; f++)
#pragma unroll
      for (int i = 0; i < 16; i++) p[f * 16 + i] = fexp2(sc[f][i] - m);
    unsigned wq[2][8];
#pragma unroll
    for (int f = 0; f < 2; f++)
#pragma unroll
      for (int i = 0; i < 8; i++)
        wq[f][i] = packbf(p[f * 16 + 2 * i], p[f * 16 + 2 * i + 1]);
#pragma unroll
    for (int off = 16; off >= 1; off >>= 1)
#pragma unroll
      for (int r = 0; r < off; r++) p[r] += p[r + off];
    l += p[0] + partner32(p[0], hi);
    // ---- P words -> PV A-frags via permlane32_swap (no LDS) ----
    s16x8 pa[4];
#pragma unroll
    for (int f = 0; f < 2; f++)
#pragma unroll
      for (int half = 0; half < 2; half++){
        unsigned w0, w1, w2, w3;
        pswap2(wq[f][half * 4 + 0], wq[f][half * 4 + 2], w0, w2);
        pswap2(wq[f][half * 4 + 1], wq[f][half * 4 + 3], w1, w3);
        u32x4 uv = { w0, w1, w2, w3 };
        pa[f * 2 + half] = __builtin_bit_cast(s16x8, uv);
      }
    // ---- PV: O += P V, B = V^T chunk ----
    __builtin_amdgcn_s_setprio(1);
#pragma unroll
    for (int ks = 0; ks < 4; ks++)
#pragma unroll
      for (int df = 0; df < 2; df++){
        int row = df * 32 + col;
        s16x8 vb = *(const s16x8*)(&VL[cur][row * 64 + ((ks * 2 + hi) ^ (row & 7)) * 8]);
        oacc[df] = mf32(pa[ks], vb, oacc[df]);
      }
    __builtin_amdgcn_s_setprio(0);
    if (hasNext) __syncthreads();            // drains stage loads (vmcnt) + protects buffers
    cur ^= 1;
  }

  const int b = bh >> 3, h = bh & 7;
  float lf[16];
#pragma unroll
  for (int r = 0; r < 16; r++) lf[r] = __shfl(l, crow[r], 64);
#pragma unroll
  for (int r = 0; r < 16; r++){
    int qq = B0 + 4 * crow[r] + w;
    float inv = 1.0f / lf[r];
    O[(size_t)(b * 1024 + qq) * 512 + h * 64 + col]      = f2b(oacc[0][r] * inv);
    O[(size_t)(b * 1024 + qq) * 512 + h * 64 + 32 + col] = f2b(oacc[1][r] * inv);
  }
}

// ---------------- final GEMM: BK=64 dbuf, swizzled 128B rows, f32 out ----------------
__global__ __launch_bounds__(256, 2) void k_gemm_out(const short* __restrict__ X,
                                                     const short* __restrict__ Wt,
                                                     float* __restrict__ C){
  __shared__ __align__(16) short Al[2][8192];   // [128 rows][64 k] swizzled 16KB each
  __shared__ __align__(16) short Bl[2][8192];
  const int t = threadIdx.x;
  const int w = t >> 6, lane = t & 63, fr = lane & 15, fg = lane >> 4;
  const int bm = blockIdx.x * 128, bn = blockIdx.y * 128;
  const int wm = (w >> 1) * 64, wn = (w & 1) * 64;

  auto stage = [&](int buf, int k0){
#pragma unroll
    for (int q = 0; q < 4; q++){
      int lin = q * 256 + t;
      int row = lin >> 3, sl = lin & 7;
      int gs = (sl ^ (row & 7)) * 8;
      gload_lds16(X  + (size_t)(bm + row) * 512 + k0 + gs, &Al[buf][(q * 256 + w * 64) * 8]);
      gload_lds16(Wt + (size_t)(bn + row) * 512 + k0 + gs, &Bl[buf][(q * 256 + w * 64) * 8]);
    }
  };

  f32x4 acc[4][4] = {};
  stage(0, 0);
  __syncthreads();
  int cur = 0;
  for (int t8 = 0; t8 < 8; ++t8){
    if (t8 < 7) stage(cur ^ 1, (t8 + 1) * 64);
#pragma unroll
    for (int kk = 0; kk < 2; kk++){
      s16x8 af[4], bv[4];
#pragma unroll
      for (int f = 0; f < 4; f++){
        int rowa = wm + f * 16 + fr;
        af[f] = *(const s16x8*)(&Al[cur][rowa * 64 + ((kk * 4 + fg) ^ (rowa & 7)) * 8]);
        int rowb = wn + f * 16 + fr;
        bv[f] = *(const s16x8*)(&Bl[cur][rowb * 64 + ((kk * 4 + fg) ^ (rowb & 7)) * 8]);
      }
#pragma unroll
      for (int i = 0; i < 4; i++)
#pragma unroll
        for (int jj = 0; jj < 4; jj++)
          acc[i][jj] = mf(af[i], bv[jj], acc[i][jj]);
    }
    __syncthreads();
    cur ^= 1;
  }
  const int row0 = bm + wm + fg * 4;
  const int col0 = bn + wn + fr;
#pragma unroll
  for (int i = 0; i < 4; i++)
#pragma unroll
    for (int jj = 0; jj < 4; jj++)
#pragma unroll
      for (int r = 0; r < 4; r++)
        C[(size_t)(row0 + i * 16 + r) * 512 + col0 + jj * 16] = acc[i][jj][r];
}

extern "C" void kernel_launch(void* const* d_in, const int* in_sizes, int n_in,
                              void* d_out, int out_size, void* d_ws, size_t ws_size,
                              hipStream_t stream){
  const float* query  = (const float*)d_in[0];
  const float* value  = (const float*)d_in[1];
  const float* key_in = (const float*)d_in[2];
  const float* Wq     = (const float*)d_in[3];
  const float* Wk     = (const float*)d_in[4];
  const float* Wv     = (const float*)d_in[5];
  const float* Wo     = (const float*)d_in[6];

  char* ws = (char*)d_ws;
  const size_t MB = 1ull << 20;
  short* Xb   = (short*)(ws);                    // 24 MB: Xq,Xk,Xv bf16 (Xq reused as Oa)
  short* Wcat = (short*)(ws + 24 * MB);          // 2 MB: Wq,Wk,Wv,Wo transposed
  float* tab  = (float*)(ws + 26 * MB);          // 256 KB
  short* Qa   = (short*)(ws + 26 * MB + 256 * 1024);   // 8 MB
  short* Ka   = (short*)((char*)Qa + 8 * MB);          // 8 MB
  short* Va   = (short*)((char*)Ka + 8 * MB);          // 8 MB  (ends at 50.25 MB)
  short* Oa   = Xb;                              // reuse Xq region after k_qkv
  short* Wot  = Wcat + 786432;                   // Wo^T block

  k_conv3<<<dim3(4096, 1, 3), 256, 0, stream>>>(query, key_in, value, Xb);
  k_wt4<<<dim3(16, 16, 4), dim3(32, 8), 0, stream>>>(Wq, Wk, Wv, Wo, Wcat);
  k_table<<<128, 256, 0, stream>>>(tab);

  k_qkv<<<dim3(64, 12), 256, 0, stream>>>(Xb, Wcat, tab, Qa, Ka, Va);

  k_attn<<<512, 256, 0, stream>>>(Qa, Ka, Va, Oa);

  k_gemm_out<<<dim3(64, 4), 256, 0, stream>>>(Oa, Wot, (float*)d_out);
}

// Round 12
// 80.991 us; speedup vs baseline: 1.0518x; 1.0368x over previous
//
#include <hip/hip_runtime.h>
#include <hip/hip_bf16.h>
#include <stdint.h>

#define DEV static __device__ __forceinline__

typedef __attribute__((ext_vector_type(8)))  short    s16x8;
typedef __attribute__((ext_vector_type(4)))  short    s16x4;
typedef __attribute__((ext_vector_type(8)))  __bf16   bf16x8;
typedef __attribute__((ext_vector_type(2)))  __bf16   bf16x2;
typedef __attribute__((ext_vector_type(4)))  float    f32x4;
typedef __attribute__((ext_vector_type(16))) float    f32x16;
typedef __attribute__((ext_vector_type(2)))  unsigned u32x2;
typedef __attribute__((ext_vector_type(4)))  unsigned u32x4;

// counted-vmcnt wait (T4): never drain to 0 in the main loop.  sched_barrier
// fences compiler motion across the wait (rule #18).
#define WAIT_VMCNT(N) do{ asm volatile("s_waitcnt vmcnt(" #N ")" ::: "memory"); \
                          __builtin_amdgcn_sched_barrier(0); }while(0)
DEV void barrier_raw(){ __builtin_amdgcn_sched_barrier(0); __builtin_amdgcn_s_barrier(); }

DEV short f2b(float f){           // round-to-nearest-even f32 -> bf16
  union{float f; uint32_t i;} x; x.f = f;
  uint32_t r = x.i + 0x7FFFu + ((x.i >> 16) & 1u);
  return (short)(r >> 16);
}
DEV unsigned packbf(float a, float b){   // v_cvt_pk_bf16_f32 path (RTNE)
  bf16x2 v = { (__bf16)a, (__bf16)b };
  return __builtin_bit_cast(unsigned, v);
}
DEV bf16x8 as_bf(s16x8 v){ return __builtin_bit_cast(bf16x8, v); }
DEV float fexp2(float x){ return __builtin_amdgcn_exp2f(x); }   // v_exp_f32: 2^x
DEV f32x4 mf(s16x8 a, s16x8 b, f32x4 c){
  return __builtin_amdgcn_mfma_f32_16x16x32_bf16(as_bf(a), as_bf(b), c, 0, 0, 0);
}
DEV f32x16 mf32(s16x8 a, s16x8 b, f32x16 c){
  return __builtin_amdgcn_mfma_f32_32x32x16_bf16(as_bf(a), as_bf(b), c, 0, 0, 0);
}

DEV void gload_lds16(const void* g, void* l){
  __builtin_amdgcn_global_load_lds((const __attribute__((address_space(1))) void*)g,
                                   (__attribute__((address_space(3))) void*)l, 16, 0, 0);
}

#if __has_builtin(__builtin_amdgcn_permlane32_swap)
DEV void pswap2(unsigned a, unsigned b, unsigned& x, unsigned& y){
  u32x2 rr = __builtin_amdgcn_permlane32_swap(a, b, false, false);
  x = rr[0]; y = rr[1];
}
DEV float partner32(float v, int hi){
  unsigned u = __builtin_bit_cast(unsigned, v);
  u32x2 rr = __builtin_amdgcn_permlane32_swap(u, u, false, false);
  return __builtin_bit_cast(float, hi ? rr[0] : rr[1]);
}
#else
DEV void pswap2(unsigned a, unsigned b, unsigned& x, unsigned& y){
  unsigned pa_ = (unsigned)__shfl_xor((int)a, 32, 64);
  unsigned pb_ = (unsigned)__shfl_xor((int)b, 32, 64);
  int lo = ((threadIdx.x & 63) < 32);
  x = lo ? a   : pb_;
  y = lo ? pa_ : b;
}
DEV float partner32(float v, int hi){ (void)hi; return __shfl_xor(v, 32, 64); }
#endif

// ---------------- fused convert f32 -> bf16 for query/key_in/value (HBM-roofline stream) ----------------
__global__ __launch_bounds__(256) void k_conv3(const float* __restrict__ q,
                                               const float* __restrict__ k,
                                               const float* __restrict__ v,
                                               short* __restrict__ out){
  int z = blockIdx.z;
  const float* in = (z == 0) ? q : (z == 1) ? k : v;
  int i = (blockIdx.x * 256 + threadIdx.x) * 4;
  float4 val = *(const float4*)(in + i);
  short o[4] = { f2b(val.x), f2b(val.y), f2b(val.z), f2b(val.w) };
  *(uint2*)(out + (size_t)z * 4194304 + i) = *(uint2*)o;
}

// ------------- fused weight transpose+convert: 4x w[512][512] f32 -> wt[n][k] bf16 -------------
__global__ __launch_bounds__(256) void k_wt4(const float* __restrict__ w0,
                                             const float* __restrict__ w1,
                                             const float* __restrict__ w2,
                                             const float* __restrict__ w3,
                                             short* __restrict__ wt){
  __shared__ float tile[32][33];
  int z = blockIdx.z;
  const float* w = (z == 0) ? w0 : (z == 1) ? w1 : (z == 2) ? w2 : w3;
  short* o = wt + (size_t)z * 262144;
  int bx = blockIdx.x * 32, by = blockIdx.y * 32;   // bx: n-block, by: k-block
  int tx = threadIdx.x, ty = threadIdx.y;           // (32, 8)
  for (int j = 0; j < 32; j += 8)
    tile[ty + j][tx] = w[(size_t)(by + ty + j) * 512 + bx + tx];
  __syncthreads();
  for (int j = 0; j < 32; j += 8)
    o[(size_t)(bx + ty + j) * 512 + by + tx] = f2b(tile[tx][ty + j]);
}

// ---------------- RoPE cos/sin table: tab[s][j][{cos,sin}], s<1024, j<32 ----------------
__global__ __launch_bounds__(256) void k_table(float* __restrict__ tab){
  int idx = blockIdx.x * 256 + threadIdx.x;   // 32768
  int s = idx >> 5, j = idx & 31;
  float inv = __expf(-(float)j * (1.0f / 32.0f) * logf(10000.0f));
  float ang = (float)s * inv;
  tab[idx * 2 + 0] = cosf(ang);
  tab[idx * 2 + 1] = sinf(ang);
}

// ---------------- QKV GEMM (bf16 in) + RoPE/layout epilogues ----------------
// 128x128 tile, BK=32, 3-buffer depth-2 prefetch with counted vmcnt (T3+T4).
__global__ __launch_bounds__(256) void k_qkv(const short* __restrict__ Xb,
                                             const short* __restrict__ Wcat,
                                             const float* __restrict__ tab,
                                             short* __restrict__ Qa,
                                             short* __restrict__ Ka,
                                             short* __restrict__ Vt){
  __shared__ __align__(16) short Al[3][4096];    // [128 rows][32 k] swizzled
  __shared__ __align__(16) short Bl[3][4096];
  const int t = threadIdx.x, w = t >> 6, lane = t & 63, fr = lane & 15, fg = lane >> 4;
  const int sel = blockIdx.y >> 2;
  const short* X = Xb + (size_t)sel * 4194304;
  const int bm = blockIdx.x * 128, bn = blockIdx.y * 128;
  const int wm = (w >> 1) * 64, wn = (w & 1) * 64;

  auto stage = [&](int buf, int k0){             // 4 gload_lds per wave
#pragma unroll
    for (int q = 0; q < 2; q++){
      int lin = q * 256 + t;
      int row = lin >> 2, sl = lin & 3;
      int gs = (sl ^ (row & 3)) * 8;             // pre-swizzled global source (rule #21)
      gload_lds16(X    + (size_t)(bm + row) * 512 + k0 + gs, &Al[buf][(q * 256 + w * 64) * 8]);
      gload_lds16(Wcat + (size_t)(bn + row) * 512 + k0 + gs, &Bl[buf][(q * 256 + w * 64) * 8]);
    }
  };

  f32x4 acc[4][4] = {};
  stage(0, 0);
  stage(1, 32);
  for (int t16 = 0; t16 < 16; ++t16){
    barrier_raw();                               // buf (t16+2)%3 free of readers
    int kc = t16 + 2; if (kc > 15) kc = 15;      // uniform tail (dummy re-stage)
    stage((t16 + 2) % 3, kc * 32);
    WAIT_VMCNT(8);                               // this body's loads landed; 2 stages fly
    barrier_raw();
    const int cur = t16 % 3;
    s16x8 af[4], bv[4];
#pragma unroll
    for (int f = 0; f < 4; f++){
      int ra = wm + f * 16 + fr;
      af[f] = *(const s16x8*)(&Al[cur][ra * 32 + ((fg ^ (ra & 3)) * 8)]);
      int rb = wn + f * 16 + fr;
      bv[f] = *(const s16x8*)(&Bl[cur][rb * 32 + ((fg ^ (rb & 3)) * 8)]);
    }
#pragma unroll
    for (int i = 0; i < 4; i++)
#pragma unroll
      for (int jj = 0; jj < 4; jj++)
        acc[i][jj] = mf(af[i], bv[jj], acc[i][jj]);
  }

  const int row0 = bm + wm + fg * 4;         // + i*16 + r
  const int b = row0 >> 10;
  const int s_base = row0 & 1023;
  const int hh = (((blockIdx.y & 3) * 128) + wn) >> 6;   // head 0..7
  if (sel < 2){
    const float scale = (sel == 0) ? 0.125f * 1.44269504f : 1.0f;
    short* out = (sel == 0) ? Qa : Ka;
#pragma unroll
    for (int i = 0; i < 4; i++)
#pragma unroll
      for (int jj = 0; jj < 2; jj++){
        int d = jj * 16 + fr;                // 0..31
#pragma unroll
        for (int r = 0; r < 4; r++){
          int s = s_base + i * 16 + r;
          float2 cs = *(const float2*)(tab + (size_t)(s * 32 + d) * 2);
          float x1 = acc[i][jj][r], x2 = acc[i][jj + 2][r];
          size_t ob = ((size_t)((b * 8 + hh) * 1024 + s)) * 64 + d;
          out[ob]      = f2b((x1 * cs.x - x2 * cs.y) * scale);
          out[ob + 32] = f2b((x2 * cs.x + x1 * cs.y) * scale);
        }
      }
  } else {
#pragma unroll
    for (int i = 0; i < 4; i++)
#pragma unroll
      for (int jj = 0; jj < 4; jj++){
        int d = jj * 16 + fr;
        s16x4 pk;
#pragma unroll
        for (int r = 0; r < 4; r++) pk[r] = f2b(acc[i][jj][r]);
        size_t ob = ((size_t)((b * 8 + hh) * 64 + d)) * 1024 + s_base + i * 16;
        *(s16x4*)(Vt + ob) = pk;
      }
  }
}

// ---------------- causal flash attention: 4-wave blocks, counted-vmcnt pipeline ----------------
// Block = 256 thr (4 waves) on q rows [B0, B0+128), wave w owns rows B0 + 4c + w.
// 3 K/V buffers, depth-2 prefetch, vmcnt(8) waits (4 loads/wave/stage), raw barriers.
__global__ __launch_bounds__(256) void k_attn(const short* __restrict__ Qb,
                                              const short* __restrict__ Kb,
                                              const short* __restrict__ Vt,
                                              short* __restrict__ O){
  __shared__ __align__(16) short KL[3][4096];
  __shared__ __align__(16) short VL[3][4096];
  const int bid = blockIdx.x;
  // co-CU pairing (g, g+4): Bi sums to 7 -> 18 bodies per CU, heavy groups first
  const int BiMap[8] = {7,6,5,4, 0,1,2,3};
  const int Bi = BiMap[bid >> 6];
  const int bh = bid & 63;                   // bid%8 == bh%8 -> bh pinned to one XCD
  const int B0 = Bi * 128;
  const int nch = (B0 >> 6) + 2;             // 64-kv chunks in [0, B0+128)
  const int t = threadIdx.x, w = t >> 6, lane = t & 63;
  const int col = lane & 31, hi = lane >> 5;
  const short* Qp = Qb + (size_t)bh * 65536;
  const short* Kp = Kb + (size_t)bh * 65536;
  const short* Vp = Vt + (size_t)bh * 65536;  // V^T: [64 d][1024 kv]
  const int qrow = B0 + 4 * col + w;          // this lane's q row (softmax axis)

  s16x8 qb[4];
#pragma unroll
  for (int ks = 0; ks < 4; ks++)
    qb[ks] = *(const s16x8*)(Qp + (size_t)qrow * 64 + ks * 16 + hi * 8);

  int crow[16];
#pragma unroll
  for (int r = 0; r < 16; r++) crow[r] = (r & 3) + 8 * (r >> 2) + 4 * hi;

  f32x16 oacc[2] = {};                       // O[q(crow)][d = df*32 + col]
  float m = -1e30f, l = 0.f;

  auto stage = [&](int buf, int kv0){        // 4 gload_lds per wave
#pragma unroll
    for (int R = 0; R < 2; R++){
      int lin = R * 256 + w * 64 + lane;     // 0..511 : row = lin/8, 16B-slot = lin%8
      int row = lin >> 3, slot = lin & 7;
      int gs = ((slot ^ (row & 7)) * 8);     // inverse-swizzled global source (rule #21)
      gload_lds16(Kp + (size_t)(kv0 + row) * 64 + gs, &KL[buf][(R * 256 + w * 64) * 8]);
      gload_lds16(Vp + (size_t)row * 1024 + kv0 + gs, &VL[buf][(R * 256 + w * 64) * 8]);
    }
  };

  stage(0, 0);
  stage(1, (nch > 1 ? 64 : 0));

  for (int i = 0; i < nch; ++i){
    const int kv0 = i * 64;
    barrier_raw();                           // buf (i+2)%3 free of readers
    int kc = i + 2; if (kc > nch - 1) kc = nch - 1;   // uniform tail
    stage((i + 2) % 3, kc * 64);
    WAIT_VMCNT(8);                           // chunk-i loads landed; 2 stages in flight
    barrier_raw();
    const int cur = i % 3;
    // ---- QK^T (swapped): D[kv][q], A = K chunk, B = Q ----
    __builtin_amdgcn_s_setprio(1);
    f32x16 sc[2];
#pragma unroll
    for (int f = 0; f < 2; f++){
      f32x16 s = {};
      int row = f * 32 + col, rx = row & 7;
#pragma unroll
      for (int ks = 0; ks < 4; ks++){
        s16x8 ka = *(const s16x8*)(&KL[cur][row * 64 + ((ks * 2 + hi) ^ rx) * 8]);
        s = mf32(ka, qb[ks], s);
      }
      sc[f] = s;
    }
    __builtin_amdgcn_s_setprio(0);
    // ---- causal mask (bodies overlapping the q range) ----
    if (kv0 >= B0){
#pragma unroll
      for (int f = 0; f < 2; f++)
#pragma unroll
        for (int r = 0; r < 16; r++){
          int kv = kv0 + f * 32 + crow[r];
          if (kv > qrow) sc[f][r] = -1e30f;
        }
    }
    // ---- softmax: tree max, defer-max rescale ----
    float mx[16];
#pragma unroll
    for (int r = 0; r < 16; r++) mx[r] = fmaxf(sc[0][r], sc[1][r]);
#pragma unroll
    for (int off = 8; off >= 1; off >>= 1)
#pragma unroll
      for (int r = 0; r < off; r++) mx[r] = fmaxf(mx[r], mx[r + off]);
    float tm = fmaxf(mx[0], partner32(mx[0], hi));
    if (!__all(tm <= m + 8.f)){
      float mn = fmaxf(m, tm);
      float corr = fexp2(m - mn);
      m = mn;
      l *= corr;
      float cpv[16];
#pragma unroll
      for (int r = 0; r < 16; r++) cpv[r] = __shfl(corr, crow[r], 64);
#pragma unroll
      for (int r = 0; r < 16; r++){ oacc[0][r] *= cpv[r]; oacc[1][r] *= cpv[r]; }
    }
    // ---- P = exp2(sc - m): cvt_pk pack + tree sum ----
    float p[32];
#pragma unroll
    for (int f = 0; f < 2; f++)
#pragma unroll
      for (int i2 = 0; i2 < 16; i2++) p[f * 16 + i2] = fexp2(sc[f][i2] - m);
    unsigned wq[2][8];
#pragma unroll
    for (int f = 0; f < 2; f++)
#pragma unroll
      for (int i2 = 0; i2 < 8; i2++)
        wq[f][i2] = packbf(p[f * 16 + 2 * i2], p[f * 16 + 2 * i2 + 1]);
#pragma unroll
    for (int off = 16; off >= 1; off >>= 1)
#pragma unroll
      for (int r = 0; r < off; r++) p[r] += p[r + off];
    l += p[0] + partner32(p[0], hi);
    // ---- P words -> PV A-frags via permlane32_swap (no LDS) ----
    s16x8 pa[4];
#pragma unroll
    for (int f = 0; f < 2; f++)
#pragma unroll
      for (int half = 0; half < 2; half++){
        unsigned w0, w1, w2, w3;
        pswap2(wq[f][half * 4 + 0], wq[f][half * 4 + 2], w0, w2);
        pswap2(wq[f][half * 4 + 1], wq[f][half * 4 + 3], w1, w3);
        u32x4 uv = { w0, w1, w2, w3 };
        pa[f * 2 + half] = __builtin_bit_cast(s16x8, uv);
      }
    // ---- PV: O += P V, B = V^T chunk ----
    __builtin_amdgcn_s_setprio(1);
#pragma unroll
    for (int ks = 0; ks < 4; ks++)
#pragma unroll
      for (int df = 0; df < 2; df++){
        int row = df * 32 + col;
        s16x8 vb = *(const s16x8*)(&VL[cur][row * 64 + ((ks * 2 + hi) ^ (row & 7)) * 8]);
        oacc[df] = mf32(pa[ks], vb, oacc[df]);
      }
    __builtin_amdgcn_s_setprio(0);
  }

  const int b = bh >> 3, h = bh & 7;
  float lf[16];
#pragma unroll
  for (int r = 0; r < 16; r++) lf[r] = __shfl(l, crow[r], 64);
#pragma unroll
  for (int r = 0; r < 16; r++){
    int qq = B0 + 4 * crow[r] + w;
    float inv = 1.0f / lf[r];
    O[(size_t)(b * 1024 + qq) * 512 + h * 64 + col]      = f2b(oacc[0][r] * inv);
    O[(size_t)(b * 1024 + qq) * 512 + h * 64 + 32 + col] = f2b(oacc[1][r] * inv);
  }
}

// ---------------- final GEMM: BK=64, 3-buffer counted-vmcnt pipeline, f32 out ----------------
__global__ __launch_bounds__(256) void k_gemm_out(const short* __restrict__ X,
                                                  const short* __restrict__ Wt,
                                                  float* __restrict__ C){
  __shared__ __align__(16) short Al[3][8192];   // [128 rows][64 k] swizzled
  __shared__ __align__(16) short Bl[3][8192];
  const int t = threadIdx.x;
  const int w = t >> 6, lane = t & 63, fr = lane & 15, fg = lane >> 4;
  const int bm = blockIdx.x * 128, bn = blockIdx.y * 128;
  const int wm = (w >> 1) * 64, wn = (w & 1) * 64;

  auto stage = [&](int buf, int k0){            // 8 gload_lds per wave
#pragma unroll
    for (int q = 0; q < 4; q++){
      int lin = q * 256 + t;
      int row = lin >> 3, sl = lin & 7;
      int gs = (sl ^ (row & 7)) * 8;
      gload_lds16(X  + (size_t)(bm + row) * 512 + k0 + gs, &Al[buf][(q * 256 + w * 64) * 8]);
      gload_lds16(Wt + (size_t)(bn + row) * 512 + k0 + gs, &Bl[buf][(q * 256 + w * 64) * 8]);
    }
  };

  f32x4 acc[4][4] = {};
  stage(0, 0);
  stage(1, 64);
  for (int t8 = 0; t8 < 8; ++t8){
    barrier_raw();
    int kc = t8 + 2; if (kc > 7) kc = 7;
    stage((t8 + 2) % 3, kc * 64);
    WAIT_VMCNT(16);
    barrier_raw();
    const int cur = t8 % 3;
#pragma unroll
    for (int kk = 0; kk < 2; kk++){
      s16x8 af[4], bv[4];
#pragma unroll
      for (int f = 0; f < 4; f++){
        int rowa = wm + f * 16 + fr;
        af[f] = *(const s16x8*)(&Al[cur][rowa * 64 + ((kk * 4 + fg) ^ (rowa & 7)) * 8]);
        int rowb = wn + f * 16 + fr;
        bv[f] = *(const s16x8*)(&Bl[cur][rowb * 64 + ((kk * 4 + fg) ^ (rowb & 7)) * 8]);
      }
#pragma unroll
      for (int i = 0; i < 4; i++)
#pragma unroll
        for (int jj = 0; jj < 4; jj++)
          acc[i][jj] = mf(af[i], bv[jj], acc[i][jj]);
    }
  }
  const int row0 = bm + wm + fg * 4;
  const int col0 = bn + wn + fr;
#pragma unroll
  for (int i = 0; i < 4; i++)
#pragma unroll
    for (int jj = 0; jj < 4; jj++)
#pragma unroll
      for (int r = 0; r < 4; r++)
        C[(size_t)(row0 + i * 16 + r) * 512 + col0 + jj * 16] = acc[i][jj][r];
}

extern "C" void kernel_launch(void* const* d_in, const int* in_sizes, int n_in,
                              void* d_out, int out_size, void* d_ws, size_t ws_size,
                              hipStream_t stream){
  const float* query  = (const float*)d_in[0];
  const float* value  = (const float*)d_in[1];
  const float* key_in = (const float*)d_in[2];
  const float* Wq     = (const float*)d_in[3];
  const float* Wk     = (const float*)d_in[4];
  const float* Wv     = (const float*)d_in[5];
  const float* Wo     = (const float*)d_in[6];

  char* ws = (char*)d_ws;
  const size_t MB = 1ull << 20;
  short* Xb   = (short*)(ws);                    // 24 MB: Xq,Xk,Xv bf16 (Xq reused as Oa)
  short* Wcat = (short*)(ws + 24 * MB);          // 2 MB: Wq,Wk,Wv,Wo transposed
  float* tab  = (float*)(ws + 26 * MB);          // 256 KB
  short* Qa   = (short*)(ws + 26 * MB + 256 * 1024);   // 8 MB
  short* Ka   = (short*)((char*)Qa + 8 * MB);          // 8 MB
  short* Va   = (short*)((char*)Ka + 8 * MB);          // 8 MB  (ends at 50.25 MB)
  short* Oa   = Xb;                              // reuse Xq region after k_qkv
  short* Wot  = Wcat + 786432;                   // Wo^T block

  k_conv3<<<dim3(4096, 1, 3), 256, 0, stream>>>(query, key_in, value, Xb);
  k_wt4<<<dim3(16, 16, 4), dim3(32, 8), 0, stream>>>(Wq, Wk, Wv, Wo, Wcat);
  k_table<<<128, 256, 0, stream>>>(tab);

  k_qkv<<<dim3(64, 12), 256, 0, stream>>>(Xb, Wcat, tab, Qa, Ka, Va);

  k_attn<<<512, 256, 0, stream>>>(Qa, Ka, Va, Oa);

  k_gemm_out<<<dim3(64, 4), 256, 0, stream>>>(Oa, Wot, (float*)d_out);
}